// Round 5
// baseline (133.226 us; speedup 1.0000x reference)
//
#include <hip/hip_runtime.h>

#define TPB 256
#define NT_ 2048
#define NQ_ 257
#define EPT 8              // NT_/TPB
#define BW 16              // band half-width of T^-1 (float band)
#define BD (2*BW+1)        // 33
#define BAND_BYTES (BD*256*4)
#define H_P 0.00390625     // p spacing = 1/256, exact in fp32/fp64

__device__ __forceinline__ double shfl_down_f64(double x, int off) {
  union { double d; int i[2]; } u; u.d = x;
  u.i[0] = __shfl_down(u.i[0], off, 64);
  u.i[1] = __shfl_down(u.i[1], off, 64);
  return u.d;
}

// ---------------- setup: banded inverse of T = (1/256)*tridiag(1,4,1), 255x255 --------
// p is exactly linspace(0,1,257) -> h = 1/256 uniform. Pivot ratios d_i = 4 - 1/d_{i-1}
// converge to 2+sqrt(3) in <15 steps. bandS[d][i] = Tinv[i][i+d-BW] as float.
// Also zeroes the completion counter used by w2_main's fused final reduction.
__global__ void w2_setup(float* __restrict__ bandS, int* __restrict__ counter) {
  __shared__ double sh_L[256];
  __shared__ double sh_winv[256];
  const int tid = threadIdx.x;
  if (tid == 0) *counter = 0;
  if (tid < 255) {
    double d, dm;
    if (tid >= 20) {
      d = dm = 3.7320508075688772935;          // 2+sqrt(3), fully converged
    } else {
      d = 4.0; dm = 0.0;
      for (int i = 1; i <= tid; i++) { dm = d; d = 4.0 - 1.0 / d; }
    }
    sh_winv[tid] = 256.0 / d;                  // 1/w_i, w_i = h*d_i
    sh_L[tid] = (tid == 0) ? 0.0 : 1.0 / dm;   // L_i = h*winv_{i-1} = 1/d_{i-1}
  }
  __syncthreads();
  const int j = tid;
  const double H = H_P;
  if (j < 255) {
    double y[BW + 1];
    y[0] = 1.0;
    #pragma unroll
    for (int m = 1; m <= BW; m++) {
      int i = j + m;
      y[m] = (i <= 254) ? (-sh_L[i] * y[m - 1]) : 0.0;
    }
    double xn = 0.0;
    #pragma unroll
    for (int m = BW; m >= 0; m--) {
      int i = j + m;
      double val = 0.0;
      if (i <= 254) {
        double num = y[m] - ((i < 254) ? H * xn : 0.0);
        val = num * sh_winv[i];
        xn = val;
      }
      bandS[(m + BW) * 256 + j] = (float)val;
    }
    #pragma unroll
    for (int m = -1; m >= -BW; m--) {
      int i = j + m;
      double val = 0.0;
      if (i >= 0) {
        val = (-H * xn) * sh_winv[i];
        xn = val;
      }
      bandS[(m + BW) * 256 + j] = (float)val;
    }
  } else {
    for (int mm = 0; mm < BD; mm++) bandS[mm * 256 + j] = 0.0f;
  }
}

// ---------------- main: one block per trace; fused final reduce via last-block --------
__global__ __launch_bounds__(TPB) void w2_main(
    const float* __restrict__ f, const float* __restrict__ obs,
    const float* __restrict__ t, const float* __restrict__ bandS,
    double* __restrict__ row_out, int* __restrict__ counter,
    float* __restrict__ out) {
  __shared__ float s_q[NQ_];
  __shared__ float s_rhs[255 + 2 * BW];   // 287
  __shared__ float s_M[NQ_];
  __shared__ float4 s_coef[256];          // {q, b, c, d} per segment
  __shared__ float s_wf[4];
  __shared__ float s_wf2[4];
  __shared__ double s_wd[4];
  __shared__ double s_misc[2];
  __shared__ int s_flag;

  const int tid = threadIdx.x;
  const int lane = tid & 63;
  const int wid = tid >> 6;
  const int row = blockIdx.x;
  const int base = tid * EPT;
  const int emax = (tid == TPB - 1) ? EPT - 1 : EPT;

  const double dx = (double)t[1] - (double)t[0];

  float tl[EPT + 1];
  {
    const float4 a = *reinterpret_cast<const float4*>(t + base);
    const float4 b = *reinterpret_cast<const float4*>(t + base + 4);
    tl[0] = a.x; tl[1] = a.y; tl[2] = a.z; tl[3] = a.w;
    tl[4] = b.x; tl[5] = b.y; tl[6] = b.z; tl[7] = b.w;
  }
  tl[EPT] = (tid < TPB - 1) ? t[base + EPT] : 0.0f;

  // ================= Phase A: obs^2 -> cdf scan -> quantile scatter =================
  float sA[EPT];
  float ep = 0.0f;
  {
    const float* orow = obs + (size_t)row * NT_;
    float ov[EPT + 1];
    const float4 a = *reinterpret_cast<const float4*>(orow + base);
    const float4 b = *reinterpret_cast<const float4*>(orow + base + 4);
    ov[0] = a.x; ov[1] = a.y; ov[2] = a.z; ov[3] = a.w;
    ov[4] = b.x; ov[5] = b.y; ov[6] = b.z; ov[7] = b.w;
    ov[EPT] = (tid < TPB - 1) ? orow[base + EPT] : 0.0f;
    for (int k = 0; k < emax; k++) {
      sA[k] = ov[k] * ov[k] + ov[k + 1] * ov[k + 1];
      ep += sA[k];
    }
    if (emax < EPT) sA[EPT - 1] = 0.0f;
  }
  float v = ep;
  #pragma unroll
  for (int off = 1; off < 64; off <<= 1) {
    float w = __shfl_up(v, off, 64);
    if (lane >= off) v += w;
  }
  float excl = __shfl_up(v, 1, 64);
  if (lane == 0) excl = 0.0f;
  if (lane == 63) s_wf[wid] = v;
  __syncthreads();                                   // B1
  float woff = 0.0f, tot = 0.0f;
  #pragma unroll
  for (int w = 0; w < 4; w++) {
    float sw = s_wf[w];
    if (w < wid) woff += sw;
    tot += sw;
  }
  float run = woff + excl;     // exclusive prefix, bit-consistent with neighbor
  float incl = woff + v;       // inclusive, == next thread's run exactly
  float inv = 1.0f / tot;

  // scatter: p[j]=j/256 exactly; j/256 <= c  <=>  j <= 256*c (256*c exact in fp32)
  {
    float cprev = fminf(run * inv, 1.0f);
    int j = (int)(cprev * 256.0f) + 1;               // first j with p[j] > cprev
    float r = run;
    for (int k = 0; k < emax; k++) {
      float cu_uns = (k == emax - 1) ? incl : (r + sA[k]);
      r = cu_uns;
      float cu = fminf(cu_uns * 256.0f * inv * 256.0f, 65536.0f); // see below
      (void)cu;
      float cuc = fminf(cu_uns * inv, 1.0f);
      int jh = (int)(cuc * 256.0f);                  // last j with p[j] <= cu
      float tq = tl[k + 1];
      for (; j <= jh; j++) s_q[j] = tq;
    }
    if (tid == 0) s_q[0] = tl[0];                    // p[0]=0 -> cdf idx 0
    if (tid == TPB - 1) {                            // p[j] > cdf_max -> idx NT-1
      float tq = tl[EPT - 1];
      for (; j <= 256; j++) s_q[j] = tq;
    }
  }

  // ---- Phase B front half (independent of s_q): f^2 squares + wave scan ----
  const float* frow = f + (size_t)row * NT_;
  float fv[EPT + 1];
  {
    const float4 a = *reinterpret_cast<const float4*>(frow + base);
    const float4 b = *reinterpret_cast<const float4*>(frow + base + 4);
    fv[0] = a.x; fv[1] = a.y; fv[2] = a.z; fv[3] = a.w;
    fv[4] = b.x; fv[5] = b.y; fv[6] = b.z; fv[7] = b.w;
  }
  fv[EPT] = (tid < TPB - 1) ? frow[base + EPT] : 0.0f;

  float sB[EPT];
  float ep2 = 0.0f;
  for (int k = 0; k < emax; k++) {
    sB[k] = fv[k] * fv[k] + fv[k + 1] * fv[k + 1];
    ep2 += sB[k];
  }
  if (emax < EPT) sB[EPT - 1] = 0.0f;
  float v2 = ep2;
  #pragma unroll
  for (int off = 1; off < 64; off <<= 1) {
    float w = __shfl_up(v2, off, 64);
    if (lane >= off) v2 += w;
  }
  float excl2 = __shfl_up(v2, 1, 64);
  if (lane == 0) excl2 = 0.0f;
  if (lane == 63) s_wf2[wid] = v2;
  __syncthreads();                                   // B2 (s_q + s_wf2 ready)

  // scanB combine (registers) + spline rhs
  float woff2 = 0.0f, tot2 = 0.0f;
  #pragma unroll
  for (int w = 0; w < 4; w++) {
    float sw = s_wf2[w];
    if (w < wid) woff2 += sw;
    tot2 += sw;
  }
  float run2 = woff2 + excl2;
  float inv2 = 1.0f / tot2;

  if (tid < 255) {
    // slope = dq/h with h = 1/256 exactly -> *256 is the identical fp32 value
    float sl0 = (s_q[tid + 1] - s_q[tid]) * 256.0f;
    float sl1 = (s_q[tid + 2] - s_q[tid + 1]) * 256.0f;
    s_rhs[BW + tid] = 6.0f * (sl1 - sl0);
  }
  if (tid < BW) s_rhs[tid] = 0.0f;
  if (tid >= TPB - BW) s_rhs[tid + (2 * BW - 1)] = 0.0f;  // 271..286
  __syncthreads();                                   // B3

  float Mreg = 0.0f;
  if (tid < 255) {
    #pragma unroll 11
    for (int dd = 0; dd < BD; dd++)
      Mreg += bandS[dd * 256 + tid] * s_rhs[tid + dd];
  }
  if (tid < 255) s_M[tid + 1] = Mreg;
  if (tid == 0) { s_M[0] = 0.0f; s_M[256] = 0.0f; }
  __syncthreads();                                   // B4

  {
    const float h = (float)H_P;
    float q0 = s_q[tid], q1 = s_q[tid + 1];
    float Mi = s_M[tid], Mi1 = s_M[tid + 1];
    float sl = (q1 - q0) * 256.0f;
    float b = sl - h * (2.0f * Mi + Mi1) * (1.0f / 6.0f);
    float c = 0.5f * Mi;
    float d = (Mi1 - Mi) * (256.0f / 6.0f);
    s_coef[tid] = make_float4(q0, b, c, d);
  }
  __syncthreads();                                   // B5

  // ================= Phase B back half: spline eval + weighted trapz ================
  double wsum = 0.0;
  {
    float r2 = run2;
    #pragma unroll
    for (int k = 0; k < EPT; k++) {
      if (k > 0) r2 += sB[k - 1];
      float F = r2 * inv2;
      float G = F * 256.0f;                          // exact (power-of-2 scale)
      int idx = (int)ceilf(G) - 1;                   // searchsorted(p,F,'left')-1
      if (idx < 0) idx = 0;
      if (idx > 255) idx = 255;
      float frac = F - (float)idx * (float)H_P;      // F - p[idx], exact p
      float4 cf = s_coef[idx];
      float val = cf.x + frac * (cf.y + frac * (cf.z + frac * cf.w));
      float diff = tl[k] - val;
      float wv = diff * diff * fv[k];
      if (tid == 0 && k == 0) s_misc[0] = (double)wv;
      if (tid == TPB - 1 && k == EPT - 1) s_misc[1] = (double)wv;
      wsum += (double)wv;
    }
  }
  double rv = wsum;
  #pragma unroll
  for (int off = 32; off >= 1; off >>= 1) rv += shfl_down_f64(rv, off);
  if (lane == 0) s_wd[wid] = rv;
  __syncthreads();                                   // B6
  if (tid == 0) {
    double totw = s_wd[0] + s_wd[1] + s_wd[2] + s_wd[3];
    row_out[row] = (totw - 0.5 * (s_misc[0] + s_misc[1])) * dx;
    __threadfence();                                 // device-scope release of row
    int old = atomicAdd(counter, 1);
    s_flag = (old == (int)gridDim.x - 1) ? 1 : 0;
  }
  __syncthreads();                                   // B7
  if (s_flag) {
    __threadfence();                                 // acquire: see all rows
    double vv = 0.0;
    const int n = (int)gridDim.x;
    for (int i = tid; i < n; i += TPB) vv += row_out[i];
    double r = vv;
    #pragma unroll
    for (int off = 32; off >= 1; off >>= 1) r += shfl_down_f64(r, off);
    if (lane == 0) s_wd[wid] = r;
    __syncthreads();
    if (tid == 0) out[0] = (float)(s_wd[0] + s_wd[1] + s_wd[2] + s_wd[3]);
  }
}

extern "C" void kernel_launch(void* const* d_in, const int* in_sizes, int n_in,
                              void* d_out, int out_size, void* d_ws, size_t ws_size,
                              hipStream_t stream) {
  const float* f   = (const float*)d_in[0];
  const float* obs = (const float*)d_in[1];
  const float* t   = (const float*)d_in[2];
  int nt = in_sizes[2];          // 2048
  int ntr = in_sizes[0] / nt;    // 4096

  float* bandS = (float*)d_ws;
  double* rows = (double*)((char*)d_ws + BAND_BYTES);
  int* counter = (int*)((char*)d_ws + BAND_BYTES + (size_t)ntr * sizeof(double));

  hipLaunchKernelGGL(w2_setup, dim3(1), dim3(256), 0, stream, bandS, counter);
  hipLaunchKernelGGL(w2_main, dim3(ntr), dim3(TPB), 0, stream,
                     f, obs, t, bandS, rows, counter, (float*)d_out);
}

// Round 6
// 43.916 us; speedup vs baseline: 3.0336x; 3.0336x over previous
//
#include <hip/hip_runtime.h>

#define TPB 256
#define NT_ 2048
#define NQ_ 257
#define EPT 8              // NT_/TPB
#define BW 16              // band half-width of T^-1 (float band)
#define BD (2*BW+1)        // 33
#define BAND_BYTES (BD*256*4)
#define H_P 0.00390625     // p spacing = 1/256, exact in fp32/fp64

__device__ __forceinline__ double shfl_down_f64(double x, int off) {
  union { double d; int i[2]; } u; u.d = x;
  u.i[0] = __shfl_down(u.i[0], off, 64);
  u.i[1] = __shfl_down(u.i[1], off, 64);
  return u.d;
}

// ---------------- setup: banded inverse of T = (1/256)*tridiag(1,4,1), 255x255 --------
// p is exactly linspace(0,1,257) -> h = 1/256 uniform. Pivot ratios d_i = 4 - 1/d_{i-1}
// converge to 2+sqrt(3). bandS[d][i] = Tinv[i][i+d-BW] as float.
__global__ void w2_setup(float* __restrict__ bandS) {
  __shared__ double sh_L[256];
  __shared__ double sh_winv[256];
  const int tid = threadIdx.x;
  if (tid < 255) {
    double d, dm;
    if (tid >= 20) {
      d = dm = 3.7320508075688772935;          // 2+sqrt(3), fully converged
    } else {
      d = 4.0; dm = 0.0;
      for (int i = 1; i <= tid; i++) { dm = d; d = 4.0 - 1.0 / d; }
    }
    sh_winv[tid] = 256.0 / d;                  // 1/w_i, w_i = h*d_i
    sh_L[tid] = (tid == 0) ? 0.0 : 1.0 / dm;   // L_i = h*winv_{i-1} = 1/d_{i-1}
  }
  __syncthreads();
  const int j = tid;
  const double H = H_P;
  if (j < 255) {
    double y[BW + 1];
    y[0] = 1.0;
    #pragma unroll
    for (int m = 1; m <= BW; m++) {
      int i = j + m;
      y[m] = (i <= 254) ? (-sh_L[i] * y[m - 1]) : 0.0;
    }
    double xn = 0.0;
    #pragma unroll
    for (int m = BW; m >= 0; m--) {
      int i = j + m;
      double val = 0.0;
      if (i <= 254) {
        double num = y[m] - ((i < 254) ? H * xn : 0.0);
        val = num * sh_winv[i];
        xn = val;
      }
      bandS[(m + BW) * 256 + j] = (float)val;
    }
    #pragma unroll
    for (int m = -1; m >= -BW; m--) {
      int i = j + m;
      double val = 0.0;
      if (i >= 0) {
        val = (-H * xn) * sh_winv[i];
        xn = val;
      }
      bandS[(m + BW) * 256 + j] = (float)val;
    }
  } else {
    for (int mm = 0; mm < BD; mm++) bandS[mm * 256 + j] = 0.0f;
  }
}

// ---------------- main: one block per trace, fp32 pipeline ----------------
// NOTE (round 3): min-waves arg in __launch_bounds__ forces VGPR<=32 and spills
// ~75 MB scratch to HBM. Keep plain (TPB).
// NOTE (round 5): do NOT fuse the final reduce via same-address atomic counter —
// 4096 device-scope RMWs on one line serialize across XCDs (+135 us).
__global__ __launch_bounds__(TPB) void w2_main(
    const float* __restrict__ f, const float* __restrict__ obs,
    const float* __restrict__ t, const float* __restrict__ bandS,
    double* __restrict__ row_out) {
  __shared__ float s_q[NQ_];
  __shared__ float s_rhs[255 + 2 * BW];   // 287
  __shared__ float s_M[NQ_];
  __shared__ float4 s_coef[256];          // {q, b, c, d} per segment
  __shared__ float s_wf[4];
  __shared__ float s_wf2[4];
  __shared__ double s_wd[4];
  __shared__ double s_misc[2];

  const int tid = threadIdx.x;
  const int lane = tid & 63;
  const int wid = tid >> 6;
  const int row = blockIdx.x;
  const int base = tid * EPT;
  const int emax = (tid == TPB - 1) ? EPT - 1 : EPT;

  const double dx = (double)t[1] - (double)t[0];

  float tl[EPT + 1];
  {
    const float4 a = *reinterpret_cast<const float4*>(t + base);
    const float4 b = *reinterpret_cast<const float4*>(t + base + 4);
    tl[0] = a.x; tl[1] = a.y; tl[2] = a.z; tl[3] = a.w;
    tl[4] = b.x; tl[5] = b.y; tl[6] = b.z; tl[7] = b.w;
  }
  tl[EPT] = (tid < TPB - 1) ? t[base + EPT] : 0.0f;

  // ================= Phase A: obs^2 -> cdf scan -> quantile scatter =================
  float sA[EPT];
  float ep = 0.0f;
  {
    const float* orow = obs + (size_t)row * NT_;
    float ov[EPT + 1];
    const float4 a = *reinterpret_cast<const float4*>(orow + base);
    const float4 b = *reinterpret_cast<const float4*>(orow + base + 4);
    ov[0] = a.x; ov[1] = a.y; ov[2] = a.z; ov[3] = a.w;
    ov[4] = b.x; ov[5] = b.y; ov[6] = b.z; ov[7] = b.w;
    ov[EPT] = (tid < TPB - 1) ? orow[base + EPT] : 0.0f;
    for (int k = 0; k < emax; k++) {
      sA[k] = ov[k] * ov[k] + ov[k + 1] * ov[k + 1];
      ep += sA[k];
    }
    if (emax < EPT) sA[EPT - 1] = 0.0f;
  }
  float v = ep;
  #pragma unroll
  for (int off = 1; off < 64; off <<= 1) {
    float w = __shfl_up(v, off, 64);
    if (lane >= off) v += w;
  }
  float excl = __shfl_up(v, 1, 64);
  if (lane == 0) excl = 0.0f;
  if (lane == 63) s_wf[wid] = v;
  __syncthreads();                                   // B1
  float woff = 0.0f, tot = 0.0f;
  #pragma unroll
  for (int w = 0; w < 4; w++) {
    float sw = s_wf[w];
    if (w < wid) woff += sw;
    tot += sw;
  }
  float run = woff + excl;     // exclusive prefix, bit-consistent with neighbor
  float incl = woff + v;       // inclusive, == next thread's run exactly
  float inv = 1.0f / tot;

  // scatter: p[j]=j/256 exactly; p[j] <= c  <=>  j <= 256*c (256*c exact in fp32)
  {
    float cprev = fminf(run * inv, 1.0f);
    int j = (int)(cprev * 256.0f) + 1;               // first j with p[j] > cprev
    float r = run;
    for (int k = 0; k < emax; k++) {
      float cu_uns = (k == emax - 1) ? incl : (r + sA[k]);
      r = cu_uns;
      float cuc = fminf(cu_uns * inv, 1.0f);
      int jh = (int)(cuc * 256.0f);                  // last j with p[j] <= cu
      float tq = tl[k + 1];
      for (; j <= jh; j++) s_q[j] = tq;
    }
    if (tid == 0) s_q[0] = tl[0];                    // p[0]=0 -> cdf idx 0
    if (tid == TPB - 1) {                            // p[j] > cdf_max -> idx NT-1
      float tq = tl[EPT - 1];
      for (; j <= 256; j++) s_q[j] = tq;
    }
  }

  // ---- Phase B front half (independent of s_q): f^2 squares + wave scan ----
  const float* frow = f + (size_t)row * NT_;
  float fv[EPT + 1];
  {
    const float4 a = *reinterpret_cast<const float4*>(frow + base);
    const float4 b = *reinterpret_cast<const float4*>(frow + base + 4);
    fv[0] = a.x; fv[1] = a.y; fv[2] = a.z; fv[3] = a.w;
    fv[4] = b.x; fv[5] = b.y; fv[6] = b.z; fv[7] = b.w;
  }
  fv[EPT] = (tid < TPB - 1) ? frow[base + EPT] : 0.0f;

  float sB[EPT];
  float ep2 = 0.0f;
  for (int k = 0; k < emax; k++) {
    sB[k] = fv[k] * fv[k] + fv[k + 1] * fv[k + 1];
    ep2 += sB[k];
  }
  if (emax < EPT) sB[EPT - 1] = 0.0f;
  float v2 = ep2;
  #pragma unroll
  for (int off = 1; off < 64; off <<= 1) {
    float w = __shfl_up(v2, off, 64);
    if (lane >= off) v2 += w;
  }
  float excl2 = __shfl_up(v2, 1, 64);
  if (lane == 0) excl2 = 0.0f;
  if (lane == 63) s_wf2[wid] = v2;
  __syncthreads();                                   // B2 (s_q + s_wf2 ready)

  float woff2 = 0.0f, tot2 = 0.0f;
  #pragma unroll
  for (int w = 0; w < 4; w++) {
    float sw = s_wf2[w];
    if (w < wid) woff2 += sw;
    tot2 += sw;
  }
  float run2 = woff2 + excl2;
  float inv2 = 1.0f / tot2;

  if (tid < 255) {
    // slope = dq/h with h = 1/256 exactly -> *256 is the identical fp32 value
    float sl0 = (s_q[tid + 1] - s_q[tid]) * 256.0f;
    float sl1 = (s_q[tid + 2] - s_q[tid + 1]) * 256.0f;
    s_rhs[BW + tid] = 6.0f * (sl1 - sl0);
  }
  if (tid < BW) s_rhs[tid] = 0.0f;
  if (tid >= TPB - BW) s_rhs[tid + (2 * BW - 1)] = 0.0f;  // 271..286
  __syncthreads();                                   // B3

  float Mreg = 0.0f;
  if (tid < 255) {
    #pragma unroll 11
    for (int dd = 0; dd < BD; dd++)
      Mreg += bandS[dd * 256 + tid] * s_rhs[tid + dd];
  }
  if (tid < 255) s_M[tid + 1] = Mreg;
  if (tid == 0) { s_M[0] = 0.0f; s_M[256] = 0.0f; }
  __syncthreads();                                   // B4

  {
    const float h = (float)H_P;
    float q0 = s_q[tid], q1 = s_q[tid + 1];
    float Mi = s_M[tid], Mi1 = s_M[tid + 1];
    float sl = (q1 - q0) * 256.0f;
    float b = sl - h * (2.0f * Mi + Mi1) * (1.0f / 6.0f);
    float c = 0.5f * Mi;
    float d = (Mi1 - Mi) * (256.0f / 6.0f);
    s_coef[tid] = make_float4(q0, b, c, d);
  }
  __syncthreads();                                   // B5

  // ================= Phase B back half: spline eval + weighted trapz ================
  double wsum = 0.0;
  {
    float r2 = run2;
    #pragma unroll
    for (int k = 0; k < EPT; k++) {
      if (k > 0) r2 += sB[k - 1];
      float F = r2 * inv2;
      float G = F * 256.0f;                          // exact (power-of-2 scale)
      int idx = (int)ceilf(G) - 1;                   // searchsorted(p,F,'left')-1
      if (idx < 0) idx = 0;
      if (idx > 255) idx = 255;
      float frac = F - (float)idx * (float)H_P;      // F - p[idx], exact p
      float4 cf = s_coef[idx];
      float val = cf.x + frac * (cf.y + frac * (cf.z + frac * cf.w));
      float diff = tl[k] - val;
      float wv = diff * diff * fv[k];
      if (tid == 0 && k == 0) s_misc[0] = (double)wv;
      if (tid == TPB - 1 && k == EPT - 1) s_misc[1] = (double)wv;
      wsum += (double)wv;
    }
  }
  double rv = wsum;
  #pragma unroll
  for (int off = 32; off >= 1; off >>= 1) rv += shfl_down_f64(rv, off);
  if (lane == 0) s_wd[wid] = rv;
  __syncthreads();                                   // B6
  if (tid == 0) {
    double totw = s_wd[0] + s_wd[1] + s_wd[2] + s_wd[3];
    row_out[row] = (totw - 0.5 * (s_misc[0] + s_misc[1])) * dx;
  }
}

__global__ void w2_reduce(const double* __restrict__ row_out, int ntr,
                          float* __restrict__ out) {
  __shared__ double s[TPB];
  int tid = threadIdx.x;
  double v = 0.0;
  for (int i = tid; i < ntr; i += TPB) v += row_out[i];
  s[tid] = v; __syncthreads();
  for (int off = TPB / 2; off > 0; off >>= 1) {
    if (tid < off) s[tid] += s[tid + off];
    __syncthreads();
  }
  if (tid == 0) out[0] = (float)s[0];
}

extern "C" void kernel_launch(void* const* d_in, const int* in_sizes, int n_in,
                              void* d_out, int out_size, void* d_ws, size_t ws_size,
                              hipStream_t stream) {
  const float* f   = (const float*)d_in[0];
  const float* obs = (const float*)d_in[1];
  const float* t   = (const float*)d_in[2];
  int nt = in_sizes[2];          // 2048
  int ntr = in_sizes[0] / nt;    // 4096

  float* bandS = (float*)d_ws;
  double* rows = (double*)((char*)d_ws + BAND_BYTES);

  hipLaunchKernelGGL(w2_setup, dim3(1), dim3(256), 0, stream, bandS);
  hipLaunchKernelGGL(w2_main, dim3(ntr), dim3(TPB), 0, stream,
                     f, obs, t, bandS, rows);
  hipLaunchKernelGGL(w2_reduce, dim3(1), dim3(TPB), 0, stream,
                     rows, ntr, (float*)d_out);
}

// Round 7
// 43.174 us; speedup vs baseline: 3.0858x; 1.0172x over previous
//
#include <hip/hip_runtime.h>

#define TPB 256
#define NT_ 2048
#define NQ_ 257
#define EPT 8              // NT_/TPB
#define BW 16              // band half-width of T^-1 (float band)
#define BD (2*BW+1)        // 33
#define BAND_BYTES (BD*256*4)
#define H_P 0.00390625     // p spacing = 1/256, exact in fp32/fp64
#define RTPB 1024

__device__ __forceinline__ double shfl_down_f64(double x, int off) {
  union { double d; int i[2]; } u; u.d = x;
  u.i[0] = __shfl_down(u.i[0], off, 64);
  u.i[1] = __shfl_down(u.i[1], off, 64);
  return u.d;
}

// ---------------- setup: banded inverse of T = (1/256)*tridiag(1,4,1), 255x255 --------
__global__ void w2_setup(float* __restrict__ bandS) {
  __shared__ double sh_L[256];
  __shared__ double sh_winv[256];
  const int tid = threadIdx.x;
  if (tid < 255) {
    double d, dm;
    if (tid >= 20) {
      d = dm = 3.7320508075688772935;          // 2+sqrt(3), fully converged
    } else {
      d = 4.0; dm = 0.0;
      for (int i = 1; i <= tid; i++) { dm = d; d = 4.0 - 1.0 / d; }
    }
    sh_winv[tid] = 256.0 / d;                  // 1/w_i, w_i = h*d_i
    sh_L[tid] = (tid == 0) ? 0.0 : 1.0 / dm;   // L_i = 1/d_{i-1}
  }
  __syncthreads();
  const int j = tid;
  const double H = H_P;
  if (j < 255) {
    double y[BW + 1];
    y[0] = 1.0;
    #pragma unroll
    for (int m = 1; m <= BW; m++) {
      int i = j + m;
      y[m] = (i <= 254) ? (-sh_L[i] * y[m - 1]) : 0.0;
    }
    double xn = 0.0;
    #pragma unroll
    for (int m = BW; m >= 0; m--) {
      int i = j + m;
      double val = 0.0;
      if (i <= 254) {
        double num = y[m] - ((i < 254) ? H * xn : 0.0);
        val = num * sh_winv[i];
        xn = val;
      }
      bandS[(m + BW) * 256 + j] = (float)val;
    }
    #pragma unroll
    for (int m = -1; m >= -BW; m--) {
      int i = j + m;
      double val = 0.0;
      if (i >= 0) {
        val = (-H * xn) * sh_winv[i];
        xn = val;
      }
      bandS[(m + BW) * 256 + j] = (float)val;
    }
  } else {
    for (int mm = 0; mm < BD; mm++) bandS[mm * 256 + j] = 0.0f;
  }
}

// ---------------- main: TWO traces per block, interleaved A/B pipelines ---------------
// NOTE (round 3): min-waves arg in __launch_bounds__ forces VGPR<=32 -> ~75 MB scratch
// spill. Plain (TPB) only.
// NOTE (round 5): no same-address atomic fusion of the final reduce (+135 us XCD tail).
// Per-row numerics are bit-identical to the 1-row version (same ops, same order).
__global__ __launch_bounds__(TPB) void w2_main(
    const float* __restrict__ f, const float* __restrict__ obs,
    const float* __restrict__ t, const float* __restrict__ bandS,
    double* __restrict__ row_out) {
  __shared__ float s_qA[NQ_], s_qB[NQ_];
  __shared__ float s_rhsA[255 + 2 * BW], s_rhsB[255 + 2 * BW];
  __shared__ float s_MA[NQ_], s_MB[NQ_];
  __shared__ float4 s_coefA[256], s_coefB[256];
  __shared__ float s_wfA[4], s_wfB[4], s_wf2A[4], s_wf2B[4];
  __shared__ double s_wdA[4], s_wdB[4];
  __shared__ double s_miscA[2], s_miscB[2];

  const int tid = threadIdx.x;
  const int lane = tid & 63;
  const int wid = tid >> 6;
  const int rowA = (int)blockIdx.x * 2;
  const int rowB = rowA + 1;
  const int base = tid * EPT;
  const int emax = (tid == TPB - 1) ? EPT - 1 : EPT;

  const double dx = (double)t[1] - (double)t[0];

  float tl[EPT + 1];
  {
    const float4 a = *reinterpret_cast<const float4*>(t + base);
    const float4 b = *reinterpret_cast<const float4*>(t + base + 4);
    tl[0] = a.x; tl[1] = a.y; tl[2] = a.z; tl[3] = a.w;
    tl[4] = b.x; tl[5] = b.y; tl[6] = b.z; tl[7] = b.w;
  }
  tl[EPT] = (tid < TPB - 1) ? t[base + EPT] : 0.0f;

  // ================= Phase A: obs^2 -> cdf scans (A,B interleaved) =================
  float sAA[EPT], sAB[EPT];
  float epA = 0.0f, epB = 0.0f;
  {
    const float* orA = obs + (size_t)rowA * NT_;
    const float* orB = obs + (size_t)rowB * NT_;
    float ovA[EPT + 1], ovB[EPT + 1];
    {
      const float4 a0 = *reinterpret_cast<const float4*>(orA + base);
      const float4 a1 = *reinterpret_cast<const float4*>(orA + base + 4);
      const float4 b0 = *reinterpret_cast<const float4*>(orB + base);
      const float4 b1 = *reinterpret_cast<const float4*>(orB + base + 4);
      ovA[0] = a0.x; ovA[1] = a0.y; ovA[2] = a0.z; ovA[3] = a0.w;
      ovA[4] = a1.x; ovA[5] = a1.y; ovA[6] = a1.z; ovA[7] = a1.w;
      ovB[0] = b0.x; ovB[1] = b0.y; ovB[2] = b0.z; ovB[3] = b0.w;
      ovB[4] = b1.x; ovB[5] = b1.y; ovB[6] = b1.z; ovB[7] = b1.w;
    }
    ovA[EPT] = (tid < TPB - 1) ? orA[base + EPT] : 0.0f;
    ovB[EPT] = (tid < TPB - 1) ? orB[base + EPT] : 0.0f;
    for (int k = 0; k < emax; k++) {
      sAA[k] = ovA[k] * ovA[k] + ovA[k + 1] * ovA[k + 1];
      sAB[k] = ovB[k] * ovB[k] + ovB[k + 1] * ovB[k + 1];
      epA += sAA[k];
      epB += sAB[k];
    }
    if (emax < EPT) { sAA[EPT - 1] = 0.0f; sAB[EPT - 1] = 0.0f; }
  }
  float vA = epA, vB = epB;
  #pragma unroll
  for (int off = 1; off < 64; off <<= 1) {
    float wA = __shfl_up(vA, off, 64);
    float wB = __shfl_up(vB, off, 64);
    if (lane >= off) { vA += wA; vB += wB; }
  }
  float exclA = __shfl_up(vA, 1, 64);
  float exclB = __shfl_up(vB, 1, 64);
  if (lane == 0) { exclA = 0.0f; exclB = 0.0f; }
  if (lane == 63) { s_wfA[wid] = vA; s_wfB[wid] = vB; }
  __syncthreads();                                   // B1
  float woffA = 0.0f, totA = 0.0f, woffB = 0.0f, totB = 0.0f;
  #pragma unroll
  for (int w = 0; w < 4; w++) {
    float swA = s_wfA[w], swB = s_wfB[w];
    if (w < wid) { woffA += swA; woffB += swB; }
    totA += swA; totB += swB;
  }
  float runA = woffA + exclA, inclA = woffA + vA, invA = 1.0f / totA;
  float runB = woffB + exclB, inclB = woffB + vB, invB = 1.0f / totB;

  // scatter: p[j]=j/256 exactly; p[j] <= c  <=>  j <= 256*c (256*c exact in fp32)
  {
    float cprev = fminf(runA * invA, 1.0f);
    int j = (int)(cprev * 256.0f) + 1;
    float r = runA;
    for (int k = 0; k < emax; k++) {
      float cu_uns = (k == emax - 1) ? inclA : (r + sAA[k]);
      r = cu_uns;
      float cuc = fminf(cu_uns * invA, 1.0f);
      int jh = (int)(cuc * 256.0f);
      float tq = tl[k + 1];
      for (; j <= jh; j++) s_qA[j] = tq;
    }
    if (tid == 0) s_qA[0] = tl[0];
    if (tid == TPB - 1) {
      float tq = tl[EPT - 1];
      for (; j <= 256; j++) s_qA[j] = tq;
    }
  }
  {
    float cprev = fminf(runB * invB, 1.0f);
    int j = (int)(cprev * 256.0f) + 1;
    float r = runB;
    for (int k = 0; k < emax; k++) {
      float cu_uns = (k == emax - 1) ? inclB : (r + sAB[k]);
      r = cu_uns;
      float cuc = fminf(cu_uns * invB, 1.0f);
      int jh = (int)(cuc * 256.0f);
      float tq = tl[k + 1];
      for (; j <= jh; j++) s_qB[j] = tq;
    }
    if (tid == 0) s_qB[0] = tl[0];
    if (tid == TPB - 1) {
      float tq = tl[EPT - 1];
      for (; j <= 256; j++) s_qB[j] = tq;
    }
  }

  // ---- Phase B front half: f^2 squares + wave scans (A,B interleaved) ----
  const float* frA = f + (size_t)rowA * NT_;
  const float* frB = f + (size_t)rowB * NT_;
  float fvA[EPT + 1], fvB[EPT + 1];
  {
    const float4 a0 = *reinterpret_cast<const float4*>(frA + base);
    const float4 a1 = *reinterpret_cast<const float4*>(frA + base + 4);
    const float4 b0 = *reinterpret_cast<const float4*>(frB + base);
    const float4 b1 = *reinterpret_cast<const float4*>(frB + base + 4);
    fvA[0] = a0.x; fvA[1] = a0.y; fvA[2] = a0.z; fvA[3] = a0.w;
    fvA[4] = a1.x; fvA[5] = a1.y; fvA[6] = a1.z; fvA[7] = a1.w;
    fvB[0] = b0.x; fvB[1] = b0.y; fvB[2] = b0.z; fvB[3] = b0.w;
    fvB[4] = b1.x; fvB[5] = b1.y; fvB[6] = b1.z; fvB[7] = b1.w;
  }
  fvA[EPT] = (tid < TPB - 1) ? frA[base + EPT] : 0.0f;
  fvB[EPT] = (tid < TPB - 1) ? frB[base + EPT] : 0.0f;

  float sBA[EPT], sBB[EPT];
  float ep2A = 0.0f, ep2B = 0.0f;
  for (int k = 0; k < emax; k++) {
    sBA[k] = fvA[k] * fvA[k] + fvA[k + 1] * fvA[k + 1];
    sBB[k] = fvB[k] * fvB[k] + fvB[k + 1] * fvB[k + 1];
    ep2A += sBA[k];
    ep2B += sBB[k];
  }
  if (emax < EPT) { sBA[EPT - 1] = 0.0f; sBB[EPT - 1] = 0.0f; }
  float v2A = ep2A, v2B = ep2B;
  #pragma unroll
  for (int off = 1; off < 64; off <<= 1) {
    float wA = __shfl_up(v2A, off, 64);
    float wB = __shfl_up(v2B, off, 64);
    if (lane >= off) { v2A += wA; v2B += wB; }
  }
  float excl2A = __shfl_up(v2A, 1, 64);
  float excl2B = __shfl_up(v2B, 1, 64);
  if (lane == 0) { excl2A = 0.0f; excl2B = 0.0f; }
  if (lane == 63) { s_wf2A[wid] = v2A; s_wf2B[wid] = v2B; }
  __syncthreads();                                   // B2 (s_q* + s_wf2* ready)

  float woff2A = 0.0f, tot2A = 0.0f, woff2B = 0.0f, tot2B = 0.0f;
  #pragma unroll
  for (int w = 0; w < 4; w++) {
    float swA = s_wf2A[w], swB = s_wf2B[w];
    if (w < wid) { woff2A += swA; woff2B += swB; }
    tot2A += swA; tot2B += swB;
  }
  float run2A = woff2A + excl2A, inv2A = 1.0f / tot2A;
  float run2B = woff2B + excl2B, inv2B = 1.0f / tot2B;

  if (tid < 255) {
    float sl0A = (s_qA[tid + 1] - s_qA[tid]) * 256.0f;
    float sl1A = (s_qA[tid + 2] - s_qA[tid + 1]) * 256.0f;
    s_rhsA[BW + tid] = 6.0f * (sl1A - sl0A);
    float sl0B = (s_qB[tid + 1] - s_qB[tid]) * 256.0f;
    float sl1B = (s_qB[tid + 2] - s_qB[tid + 1]) * 256.0f;
    s_rhsB[BW + tid] = 6.0f * (sl1B - sl0B);
  }
  if (tid < BW) { s_rhsA[tid] = 0.0f; s_rhsB[tid] = 0.0f; }
  if (tid >= TPB - BW) {
    s_rhsA[tid + (2 * BW - 1)] = 0.0f;
    s_rhsB[tid + (2 * BW - 1)] = 0.0f;
  }
  __syncthreads();                                   // B3

  float MregA = 0.0f, MregB = 0.0f;
  if (tid < 255) {
    #pragma unroll 11
    for (int dd = 0; dd < BD; dd++) {
      float w = bandS[dd * 256 + tid];               // one load feeds both rows
      MregA += w * s_rhsA[tid + dd];
      MregB += w * s_rhsB[tid + dd];
    }
  }
  if (tid < 255) { s_MA[tid + 1] = MregA; s_MB[tid + 1] = MregB; }
  if (tid == 0) { s_MA[0] = 0.0f; s_MA[256] = 0.0f; s_MB[0] = 0.0f; s_MB[256] = 0.0f; }
  __syncthreads();                                   // B4

  {
    const float h = (float)H_P;
    float q0A = s_qA[tid], q1A = s_qA[tid + 1];
    float MiA = s_MA[tid], Mi1A = s_MA[tid + 1];
    float slA = (q1A - q0A) * 256.0f;
    float bA = slA - h * (2.0f * MiA + Mi1A) * (1.0f / 6.0f);
    s_coefA[tid] = make_float4(q0A, bA, 0.5f * MiA, (Mi1A - MiA) * (256.0f / 6.0f));
    float q0B = s_qB[tid], q1B = s_qB[tid + 1];
    float MiB = s_MB[tid], Mi1B = s_MB[tid + 1];
    float slB = (q1B - q0B) * 256.0f;
    float bB = slB - h * (2.0f * MiB + Mi1B) * (1.0f / 6.0f);
    s_coefB[tid] = make_float4(q0B, bB, 0.5f * MiB, (Mi1B - MiB) * (256.0f / 6.0f));
  }
  __syncthreads();                                   // B5

  // ================= Phase B back half: spline eval + weighted trapz ================
  double wsumA = 0.0, wsumB = 0.0;
  {
    float r2A = run2A, r2B = run2B;
    #pragma unroll
    for (int k = 0; k < EPT; k++) {
      if (k > 0) { r2A += sBA[k - 1]; r2B += sBB[k - 1]; }
      float FA = r2A * inv2A;
      float FB = r2B * inv2B;
      int idxA = (int)ceilf(FA * 256.0f) - 1;        // searchsorted(p,F,'left')-1
      int idxB = (int)ceilf(FB * 256.0f) - 1;
      if (idxA < 0) idxA = 0; if (idxA > 255) idxA = 255;
      if (idxB < 0) idxB = 0; if (idxB > 255) idxB = 255;
      float fracA = FA - (float)idxA * (float)H_P;
      float fracB = FB - (float)idxB * (float)H_P;
      float4 cfA = s_coefA[idxA];
      float4 cfB = s_coefB[idxB];
      float valA = cfA.x + fracA * (cfA.y + fracA * (cfA.z + fracA * cfA.w));
      float valB = cfB.x + fracB * (cfB.y + fracB * (cfB.z + fracB * cfB.w));
      float diffA = tl[k] - valA;
      float diffB = tl[k] - valB;
      float wvA = diffA * diffA * fvA[k];
      float wvB = diffB * diffB * fvB[k];
      if (tid == 0 && k == 0) { s_miscA[0] = (double)wvA; s_miscB[0] = (double)wvB; }
      if (tid == TPB - 1 && k == EPT - 1) { s_miscA[1] = (double)wvA; s_miscB[1] = (double)wvB; }
      wsumA += (double)wvA;
      wsumB += (double)wvB;
    }
  }
  double rA = wsumA, rB = wsumB;
  #pragma unroll
  for (int off = 32; off >= 1; off >>= 1) {
    rA += shfl_down_f64(rA, off);
    rB += shfl_down_f64(rB, off);
  }
  if (lane == 0) { s_wdA[wid] = rA; s_wdB[wid] = rB; }
  __syncthreads();                                   // B6
  if (tid == 0) {
    double totwA = s_wdA[0] + s_wdA[1] + s_wdA[2] + s_wdA[3];
    double totwB = s_wdB[0] + s_wdB[1] + s_wdB[2] + s_wdB[3];
    row_out[rowA] = (totwA - 0.5 * (s_miscA[0] + s_miscA[1])) * dx;
    row_out[rowB] = (totwB - 0.5 * (s_miscB[0] + s_miscB[1])) * dx;
  }
}

__global__ __launch_bounds__(RTPB) void w2_reduce(const double* __restrict__ row_out,
                                                  int ntr, float* __restrict__ out) {
  __shared__ double s[RTPB / 64];
  int tid = threadIdx.x, lane = tid & 63, wid = tid >> 6;
  double v = 0.0;
  for (int i = tid; i < ntr; i += RTPB) v += row_out[i];
  #pragma unroll
  for (int off = 32; off >= 1; off >>= 1) v += shfl_down_f64(v, off);
  if (lane == 0) s[wid] = v;
  __syncthreads();
  if (tid == 0) {
    double tot = 0.0;
    #pragma unroll
    for (int i = 0; i < RTPB / 64; i++) tot += s[i];
    out[0] = (float)tot;
  }
}

extern "C" void kernel_launch(void* const* d_in, const int* in_sizes, int n_in,
                              void* d_out, int out_size, void* d_ws, size_t ws_size,
                              hipStream_t stream) {
  const float* f   = (const float*)d_in[0];
  const float* obs = (const float*)d_in[1];
  const float* t   = (const float*)d_in[2];
  int nt = in_sizes[2];          // 2048
  int ntr = in_sizes[0] / nt;    // 4096

  float* bandS = (float*)d_ws;
  double* rows = (double*)((char*)d_ws + BAND_BYTES);

  hipLaunchKernelGGL(w2_setup, dim3(1), dim3(256), 0, stream, bandS);
  hipLaunchKernelGGL(w2_main, dim3(ntr / 2), dim3(TPB), 0, stream,
                     f, obs, t, bandS, rows);
  hipLaunchKernelGGL(w2_reduce, dim3(1), dim3(RTPB), 0, stream,
                     rows, ntr, (float*)d_out);
}